// Round 7
// baseline (224.979 us; speedup 1.0000x reference)
//
#include <hip/hip_runtime.h>

// 10 steps of anisotropic 2D heat stencil, 48x48, B=16384.
// TWO images per lane packed as v2f -> all stencil math is v_pk_*_f32 with
// zero half-mixing (horizontal neighbors are adjacent registers).
// Wave = 2 images. Lane layout 16x4: (r,c)=(lane&15, lane>>4), patch 3x12.
// Vertical halo: DPP row_shr/shl:1 with frozen reflect ghost as 'old' operand.
// Horizontal halo: 4 shfl/row + select. Frozen ghosts (reflect pad of the
// INITIAL state) are re-read from u0 each step (L1-resident) - no ghost regs.
// waves_per_eu(3,3): ~170-reg budget, guaranteed no scratch spill.

typedef float v2f __attribute__((ext_vector_type(2)));

constexpr int NXY   = 48;
constexpr int CELLS = NXY * NXY;   // 2304
constexpr int NT    = 10;
constexpr int WPB   = 4;           // waves (image-pairs) per block -> 8 images
constexpr int TPB   = 64 * WPB;

// lane i <- lane i-1 within 16-lane DPP row; invalid (i%16==0) keeps oldv
__device__ __forceinline__ float dpp_up(float oldv, float src) {
    return __int_as_float(__builtin_amdgcn_update_dpp(
        __float_as_int(oldv), __float_as_int(src), 0x111, 0xF, 0xF, false));
}
// lane i <- lane i+1; invalid (i%16==15) keeps oldv
__device__ __forceinline__ float dpp_dn(float oldv, float src) {
    return __int_as_float(__builtin_amdgcn_update_dpp(
        __float_as_int(oldv), __float_as_int(src), 0x101, 0xF, 0xF, false));
}

__global__ __launch_bounds__(TPB)
__attribute__((amdgpu_waves_per_eu(3, 3)))
void pde_heat_kernel(const float* __restrict__ u0,
                     const float* __restrict__ aw,
                     const float* __restrict__ bw,
                     float* __restrict__ out)
{
    const int lane = threadIdx.x & 63;
    const int pair = blockIdx.x * WPB + (threadIdx.x >> 6);  // image pair id
    const int r = lane & 15;         // 16 row-strips of 3 rows
    const int c = lane >> 4;         // 4 col-strips of 12 cols

    const float* __restrict__ A  = u0 + (long long)(2 * pair) * CELLS;
    const float* __restrict__ Bi = A + CELLS;
    float* __restrict__ oA = out + (long long)(2 * pair) * CELLS;
    float* __restrict__ oB = oA + CELLS;

    const int fb = r * 36 + c * 3;   // float4 index of patch origin

    // ---- load both images, interleave into (A,B) pairs ----
    v2f v[3][12];
    const float4* A4 = (const float4*)A;
    const float4* B4 = (const float4*)Bi;
    #pragma unroll
    for (int ii = 0; ii < 3; ++ii)
        #pragma unroll
        for (int k = 0; k < 3; ++k) {
            float4 a = A4[fb + 12 * ii + k];
            float4 b = B4[fb + 12 * ii + k];
            v[ii][4*k+0] = v2f{a.x, b.x};
            v[ii][4*k+1] = v2f{a.y, b.y};
            v[ii][4*k+2] = v2f{a.z, b.z};
            v[ii][4*k+3] = v2f{a.w, b.w};
        }

    // ---- coefficients (v_sin/v_cos take REVOLUTIONS: sin(2pi x) = v_sin(x)) ----
    // alpha(i) scales axis-0 diff: 0.5*dt/dx^2 = 1.152 ; beta(j): dt/dy^2 = 2.304
    const float a0 = aw[0], a1 = aw[1], a2 = aw[2];
    const float b0 = bw[0], b1 = bw[1], b2 = bw[2];
    float ca[3], cb[12];
    #pragma unroll
    for (int ii = 0; ii < 3; ++ii) {
        float y = (float)(3 * r + ii) * (1.0f / 47.0f);
        ca[ii] = 1.152f * (a0 + a1 * __builtin_amdgcn_sinf(y)
                              + a2 * __builtin_amdgcn_sinf(2.0f * y));
    }
    #pragma unroll
    for (int jj = 0; jj < 12; ++jj) {
        float x = (float)(12 * c + jj) * (1.0f / 47.0f);
        cb[jj] = 2.304f * (b0 + b1 * __builtin_amdgcn_cosf(x)
                              + b2 * __builtin_amdgcn_cosf(2.0f * x));
    }

    // ---- frozen ghost pointers into the (unmodified) input ----
    // row ghost: r==0 -> u0 row 1; r==15 -> u0 row 46 (others unused by dpp)
    const int grow = (r == 0) ? 1 : 46;
    const float* grA = A  + grow * NXY + 12 * c;
    const float* grB = Bi + grow * NXY + 12 * c;
    // col ghost: c==0 -> col 1; c==3 -> col 46 (others discarded by select)
    const int gcol = (c == 0) ? 1 : 46;
    const float* gcA = A  + 3 * r * NXY + gcol;
    const float* gcB = Bi + 3 * r * NXY + gcol;

    const int laneL = lane - 16, laneR = lane + 16;

    // ---- time loop ----
    for (int t = 0; t < NT; ++t) {
        // reload frozen row-ghosts (L1/L2-resident after first step)
        float gA[12], gB[12];
        #pragma unroll
        for (int k = 0; k < 3; ++k) {
            float4 ga = *(const float4*)(grA + 4 * k);
            float4 gb = *(const float4*)(grB + 4 * k);
            gA[4*k+0] = ga.x; gA[4*k+1] = ga.y; gA[4*k+2] = ga.z; gA[4*k+3] = ga.w;
            gB[4*k+0] = gb.x; gB[4*k+1] = gb.y; gB[4*k+2] = gb.z; gB[4*k+3] = gb.w;
        }
        // vertical halos captured before any update (dpp old = frozen ghost)
        v2f above[12], hbot[12];
        #pragma unroll
        for (int jj = 0; jj < 12; ++jj) {
            above[jj].x = dpp_up(gA[jj], v[2][jj].x);
            above[jj].y = dpp_up(gB[jj], v[2][jj].y);
            hbot[jj].x  = dpp_dn(gA[jj], v[0][jj].x);
            hbot[jj].y  = dpp_dn(gB[jj], v[0][jj].y);
        }

        #pragma unroll
        for (int ii = 0; ii < 3; ++ii) {
            v2f gc; gc.x = gcA[ii * NXY]; gc.y = gcB[ii * NXY];
            v2f hl, hr;
            hl.x = __shfl(v[ii][11].x, laneL); hl.y = __shfl(v[ii][11].y, laneL);
            hr.x = __shfl(v[ii][0].x,  laneR); hr.y = __shfl(v[ii][0].y,  laneR);
            hl = (c == 0) ? gc : hl;
            hr = (c == 3) ? gc : hr;

            v2f nrow[12];
            #pragma unroll
            for (int jj = 0; jj < 12; ++jj) {
                v2f cv = v[ii][jj];
                v2f dn = (ii < 2)  ? v[ii + 1][jj] : hbot[jj];
                v2f lf = (jj > 0)  ? v[ii][jj - 1] : hl;
                v2f rt = (jj < 11) ? v[ii][jj + 1] : hr;
                v2f t1 = (above[jj] + dn) - 2.0f * cv;   // packed
                v2f t2 = (lf + rt)        - 2.0f * cv;   // packed
                nrow[jj] = cv + ca[ii] * t1 + cb[jj] * t2; // packed fma
            }
            // rotate: above <- old row ii, row ii <- new
            #pragma unroll
            for (int jj = 0; jj < 12; ++jj) {
                above[jj] = v[ii][jj];
                v[ii][jj] = nrow[jj];
            }
        }
    }

    // ---- de-interleave + store both images ----
    float4* o4A = (float4*)oA;
    float4* o4B = (float4*)oB;
    #pragma unroll
    for (int ii = 0; ii < 3; ++ii)
        #pragma unroll
        for (int k = 0; k < 3; ++k) {
            float4 a, b;
            a.x = v[ii][4*k+0].x; b.x = v[ii][4*k+0].y;
            a.y = v[ii][4*k+1].x; b.y = v[ii][4*k+1].y;
            a.z = v[ii][4*k+2].x; b.z = v[ii][4*k+2].y;
            a.w = v[ii][4*k+3].x; b.w = v[ii][4*k+3].y;
            o4A[fb + 12 * ii + k] = a;
            o4B[fb + 12 * ii + k] = b;
        }
}

extern "C" void kernel_launch(void* const* d_in, const int* in_sizes, int n_in,
                              void* d_out, int out_size, void* d_ws, size_t ws_size,
                              hipStream_t stream) {
    const float* u0 = (const float*)d_in[0];
    const float* aw = (const float*)d_in[1];
    const float* bw = (const float*)d_in[2];
    float* out = (float*)d_out;

    const int B = in_sizes[0] / CELLS;         // 16384
    const int nPairs = B / 2;                  // 8192 waves
    pde_heat_kernel<<<nPairs / WPB, TPB, 0, stream>>>(u0, aw, bw, out);
}

// Round 8
// 89.828 us; speedup vs baseline: 2.5046x; 2.5046x over previous
//
#include <hip/hip_runtime.h>

// 10 steps of anisotropic 2D heat stencil, 48x48, B=16384.
// Wave = image. Lane layout 16x4: (r,c) = (lane&15, lane>>4), patch = 3x12 in
// registers as 6 x float2 per row -> packed v_pk_add/fma_f32 stencil math.
// Vertical halo: DPP row shifts, frozen reflect ghost as the 'old' operand.
// Horizontal halo: 2 shuffles/row. No LDS; direct float4 global load/store.
// Frozen ghosts = reflect pad of the INITIAL state (reference pads once).
// waves_per_eu(4,8): min-4 keeps a >=128-reg no-spill floor; max-8 UNCAPS
// residency (round 6's max-4 capped occupancy at 50% -> VALUBusy stuck at 60%).

typedef float v2f __attribute__((ext_vector_type(2)));

constexpr int NXY   = 48;
constexpr int CELLS = NXY * NXY;     // 2304
constexpr int NT    = 10;
constexpr int WPB   = 4;             // waves (images) per block
constexpr int TPB   = 64 * WPB;

// lane i <- lane i-1 within each 16-lane DPP row; invalid (i%16==0) keeps oldv
__device__ __forceinline__ float dpp_up(float oldv, float src) {
    return __int_as_float(__builtin_amdgcn_update_dpp(
        __float_as_int(oldv), __float_as_int(src), 0x111, 0xF, 0xF, false));
}
// lane i <- lane i+1; invalid (i%16==15) keeps oldv
__device__ __forceinline__ float dpp_dn(float oldv, float src) {
    return __int_as_float(__builtin_amdgcn_update_dpp(
        __float_as_int(oldv), __float_as_int(src), 0x101, 0xF, 0xF, false));
}
__device__ __forceinline__ v2f dpp_up2(v2f o, v2f s) {
    v2f r; r.x = dpp_up(o.x, s.x); r.y = dpp_up(o.y, s.y); return r;
}
__device__ __forceinline__ v2f dpp_dn2(v2f o, v2f s) {
    v2f r; r.x = dpp_dn(o.x, s.x); r.y = dpp_dn(o.y, s.y); return r;
}

__global__ __launch_bounds__(TPB)
__attribute__((amdgpu_waves_per_eu(4, 8)))
void pde_heat_kernel(
    const float* __restrict__ u0,
    const float* __restrict__ aw,
    const float* __restrict__ bw,
    float* __restrict__ out)
{
    const int lane = threadIdx.x & 63;
    const int img  = blockIdx.x * WPB + (threadIdx.x >> 6);
    const int r = lane & 15;         // patch-row strip (16 strips of 3 rows)
    const int c = lane >> 4;         // patch-col strip (4 strips of 12 cols)
    const float4* __restrict__ u4 = (const float4*)(u0 + (long long)img * CELLS);
    float4*       __restrict__ o4 = (float4*)(out + (long long)img * CELLS);

    const int fb = r * 36 + c * 3;   // float4 index of patch (row0, col0)

    // ---- direct load: 9 x global_load_dwordx4 -> 6 x v2f per row ----
    v2f v[3][6];
    #pragma unroll
    for (int ii = 0; ii < 3; ++ii)
        #pragma unroll
        for (int k = 0; k < 3; ++k) {
            float4 t = u4[fb + 12 * ii + k];
            v[ii][2*k]   = (v2f){t.x, t.y};
            v[ii][2*k+1] = (v2f){t.z, t.w};
        }

    // ---- coefficients (v_sin/v_cos take REVOLUTIONS: sin(2pi*x) = v_sin(x)) ----
    // alpha(i) scales axis-0 diff: 0.5*dt/dx^2 = 1.152 ; beta(j): dt/dy^2 = 2.304
    const float a0 = aw[0], a1 = aw[1], a2 = aw[2];
    const float b0 = bw[0], b1 = bw[1], b2 = bw[2];
    float ca[3];
    #pragma unroll
    for (int ii = 0; ii < 3; ++ii) {
        float y = (float)(3 * r + ii) * (1.0f / 47.0f);
        ca[ii] = 1.152f * (a0 + a1 * __builtin_amdgcn_sinf(y)
                              + a2 * __builtin_amdgcn_sinf(2.0f * y));
    }
    v2f cb2[6];
    #pragma unroll
    for (int k = 0; k < 6; ++k) {
        float x0 = (float)(12 * c + 2 * k)     * (1.0f / 47.0f);
        float x1 = (float)(12 * c + 2 * k + 1) * (1.0f / 47.0f);
        cb2[k].x = 2.304f * (b0 + b1 * __builtin_amdgcn_cosf(x0)
                                + b2 * __builtin_amdgcn_cosf(2.0f * x0));
        cb2[k].y = 2.304f * (b0 + b1 * __builtin_amdgcn_cosf(x1)
                                + b2 * __builtin_amdgcn_cosf(2.0f * x1));
    }

    // ---- frozen reflect ghosts (from INITIAL state) ----
    // top (r==0): u0 row 1 = own v[1]; bottom (r==15): row 46 = 3*15+1 = own v[1]
    // left (c==0): col 1 = v[ii][0].y; right (c==3): col 46 = elem 10 = v[ii][5].x
    v2f gV[6];
    #pragma unroll
    for (int k = 0; k < 6; ++k) gV[k] = v[1][k];
    float gH[3];
    #pragma unroll
    for (int ii = 0; ii < 3; ++ii) gH[ii] = (c == 0) ? v[ii][0].y : v[ii][5].x;

    const int laneL = lane - 16, laneR = lane + 16;

    // ---- time loop: registers + DPP + 6 shuffles/step, packed f32 math ----
    for (int t = 0; t < NT; ++t) {
        // capture old vertical halos before any update this step
        v2f hb[6], above[6];
        #pragma unroll
        for (int k = 0; k < 6; ++k) hb[k]    = dpp_dn2(gV[k], v[0][k]);
        #pragma unroll
        for (int k = 0; k < 6; ++k) above[k] = dpp_up2(gV[k], v[2][k]);

        #pragma unroll
        for (int ii = 0; ii < 3; ++ii) {
            float hl = __shfl(v[ii][5].y, laneL);   // left-neighbor's col 11
            float hr = __shfl(v[ii][0].x, laneR);   // right-neighbor's col 0
            hl = (c == 0) ? gH[ii] : hl;
            hr = (c == 3) ? gH[ii] : hr;

            // shifted row vectors for the horizontal term (v[ii] still old)
            v2f L[6], R[6];
            L[0] = (v2f){hl, v[ii][0].x};
            #pragma unroll
            for (int k = 1; k < 6; ++k) L[k] = (v2f){v[ii][k-1].y, v[ii][k].x};
            #pragma unroll
            for (int k = 0; k < 5; ++k) R[k] = (v2f){v[ii][k].y, v[ii][k+1].x};
            R[5] = (v2f){v[ii][5].y, hr};

            v2f nrow[6];
            #pragma unroll
            for (int k = 0; k < 6; ++k) {
                v2f cv    = v[ii][k];
                v2f below = (ii < 2) ? v[ii + 1][k] : hb[k];
                v2f uxx = (above[k] + below) - 2.0f * cv;   // packed
                v2f uyy = (L[k] + R[k])      - 2.0f * cv;   // packed
                nrow[k] = cv + ca[ii] * uxx + cb2[k] * uyy; // packed fma
            }
            // rotate: above <- old row ii, row ii <- new (single copy)
            #pragma unroll
            for (int k = 0; k < 6; ++k) {
                above[k] = v[ii][k];
                v[ii][k] = nrow[k];
            }
        }
    }

    // ---- direct store: 9 x global_store_dwordx4 ----
    #pragma unroll
    for (int ii = 0; ii < 3; ++ii)
        #pragma unroll
        for (int k = 0; k < 3; ++k) {
            float4 t;
            t.x = v[ii][2*k].x;   t.y = v[ii][2*k].y;
            t.z = v[ii][2*k+1].x; t.w = v[ii][2*k+1].y;
            o4[fb + 12 * ii + k] = t;
        }
}

extern "C" void kernel_launch(void* const* d_in, const int* in_sizes, int n_in,
                              void* d_out, int out_size, void* d_ws, size_t ws_size,
                              hipStream_t stream) {
    const float* u0 = (const float*)d_in[0];
    const float* aw = (const float*)d_in[1];
    const float* bw = (const float*)d_in[2];
    float* out = (float*)d_out;

    const int B = in_sizes[0] / CELLS;   // 16384
    pde_heat_kernel<<<B / WPB, TPB, 0, stream>>>(u0, aw, bw, out);
}